// Round 1
// baseline (75.386 us; speedup 1.0000x reference)
//
#include <hip/hip_runtime.h>
#include <math.h>

#define SD    128   // STATE_DIM
#define NN    129   // SD + 1
#define HID   32
#define BATCHN 512
#define ROWS  16    // batch rows per block
#define LPR   16    // lanes per row
#define HPL   2     // hidden units per lane (HID / LPR)

__global__ __launch_bounds__(256) void gnm_kernel(
    const float* __restrict__ x,        // [512,128]
    const float* __restrict__ t_p,      // [1]
    const float* __restrict__ log_amp,  // [128,12]
    const float* __restrict__ W1,       // [129,32]
    const float* __restrict__ b1,       // [32]
    const float* __restrict__ W2,       // [32,128]
    const float* __restrict__ b2,       // [128]
    float* __restrict__ out)            // [512,128]
{
    __shared__ float sW1[NN * HID];     // 16.5 KB
    __shared__ float sx[ROWS * NN];     // stride 129 breaks bank aliasing
    __shared__ float samp[SD];
    __shared__ float sw2[HID];
    __shared__ float sb2bar;

    const int tid  = threadIdx.x;
    const int base = blockIdx.x * ROWS;

    const float t     = t_p[0];
    const float emb   = sinf(t * (float)(2.0 * M_PI / 12.0));
    const int   month = (int)fmodf(t, 12.0f);

    // ---- stage W1 into LDS (coalesced) ----
    for (int i = tid; i < NN * HID; i += 256) sW1[i] = W1[i];
    // ---- stage this block's x tile ----
    for (int i = tid; i < ROWS * SD; i += 256) {
        const int r = i >> 7, n = i & 127;
        sx[r * NN + n] = x[(base + r) * SD + n];
    }
    // ---- seasonal amplitudes ----
    if (tid < SD) samp[tid] = expf(log_amp[tid * 12 + month]);
    // ---- w2bar = mean over W2 columns ----
    if (tid >= 128 && tid < 128 + HID) {
        const int h = tid - 128;
        float s = 0.f;
        for (int f = 0; f < SD; ++f) s += W2[h * SD + f];
        sw2[h] = s * (1.0f / SD);
    }
    if (tid == 160) {
        float s = 0.f;
        for (int f = 0; f < SD; ++f) s += b2[f];
        sb2bar = s * (1.0f / SD);
    }
    __syncthreads();

    const int l   = tid & (LPR - 1);
    const int r   = tid / LPR;
    const int row = base + r;
    const int h0  = l * HPL;

    // ---- z = relu(feat @ W1 + b1), 2 hidden units per lane ----
    float acc0 = b1[h0];
    float acc1 = b1[h0 + 1];
    const float* xr = &sx[r * NN];
    #pragma unroll 4
    for (int n = 0; n < SD; ++n) {
        const float f = xr[n];
        const float2 w = *(const float2*)&sW1[n * HID + h0];
        acc0 = fmaf(f, w.x, acc0);
        acc1 = fmaf(f, w.y, acc1);
    }
    {   // n = 128: the sin-embedding feature
        const float2 w = *(const float2*)&sW1[SD * HID + h0];
        acc0 = fmaf(emb, w.x, acc0);
        acc1 = fmaf(emb, w.y, acc1);
    }

    // ---- m = z . w2bar (+ b2bar), reduced over the 16 lanes of this row ----
    float part = fmaxf(acc0, 0.f) * sw2[h0] + fmaxf(acc1, 0.f) * sw2[h0 + 1];
    part += __shfl_xor(part, 1);
    part += __shfl_xor(part, 2);
    part += __shfl_xor(part, 4);
    part += __shfl_xor(part, 8);
    const float m  = part + sb2bar;
    const float sp = (m > 0.f) ? (m + log1pf(expf(-m))) : log1pf(expf(m));

    // ---- out[row, j] = amp[j] * softplus(m), 8 columns per lane ----
    float* orow = out + row * SD + l * 8;
    #pragma unroll
    for (int q = 0; q < 2; ++q) {
        const float* a = &samp[l * 8 + q * 4];
        float4 v;
        v.x = a[0] * sp; v.y = a[1] * sp; v.z = a[2] * sp; v.w = a[3] * sp;
        *(float4*)(orow + q * 4) = v;
    }
}

extern "C" void kernel_launch(void* const* d_in, const int* in_sizes, int n_in,
                              void* d_out, int out_size, void* d_ws, size_t ws_size,
                              hipStream_t stream) {
    const float* x  = (const float*)d_in[0];
    const float* t  = (const float*)d_in[1];
    const float* la = (const float*)d_in[2];
    const float* W1 = (const float*)d_in[3];
    const float* b1 = (const float*)d_in[4];
    const float* W2 = (const float*)d_in[5];
    const float* b2 = (const float*)d_in[6];
    float* out = (float*)d_out;

    gnm_kernel<<<BATCHN / ROWS, 256, 0, stream>>>(x, t, la, W1, b1, W2, b2, out);
}

// Round 2
// 69.420 us; speedup vs baseline: 1.0859x; 1.0859x over previous
//
#include <hip/hip_runtime.h>
#include <math.h>

#define SD     128   // STATE_DIM
#define NN     129   // SD + 1
#define HID    32
#define BATCHN 512
#define ROWS   16    // batch rows per block
#define LPR    16    // lanes per row
#define XS     132   // x-tile LDS stride (16B-aligned rows, 4-bank skew)

__global__ __launch_bounds__(256) void gnm_kernel(
    const float* __restrict__ x,        // [512,128]
    const float* __restrict__ t_p,      // [1]
    const float* __restrict__ log_amp,  // [128,12]
    const float* __restrict__ W1,       // [129,32]
    const float* __restrict__ b1,       // [32]
    const float* __restrict__ W2,       // [32,128]
    const float* __restrict__ b2,       // [128]
    float* __restrict__ out)            // [512,128]
{
    __shared__ float sW1[NN * HID];     // 16.5 KB
    __shared__ float sx[ROWS * XS];     // 8.25 KB
    __shared__ float samp[SD];
    __shared__ float sw2[HID];
    __shared__ float sb2bar;

    const int tid  = threadIdx.x;
    const int base = blockIdx.x * ROWS;

    const float t     = t_p[0];
    const float emb   = sinf(t * (float)(2.0 * M_PI / 12.0));
    const int   month = (int)fmodf(t, 12.0f);

    // ---- stage W1 (float4, coalesced): 4128 floats = 1032 float4 ----
    {
        const float4* g = (const float4*)W1;
        float4*       s = (float4*)sW1;
        #pragma unroll
        for (int i = tid; i < (NN * HID) / 4; i += 256) s[i] = g[i];
    }
    // ---- stage x tile (float4): 16 rows x 32 float4 ----
    {
        for (int i = tid; i < ROWS * 32; i += 256) {
            const int r = i >> 5, c = i & 31;
            ((float4*)&sx[r * XS])[c] = ((const float4*)(x + (size_t)(base + r) * SD))[c];
        }
    }

    // ---- parallel precomputes, one job per wave-group ----
    if (tid < 128) {
        // w2bar: h = tid>>2 (0..31), g = tid&3; each sums 32 floats (8 float4)
        const int h = tid >> 2, g = tid & 3;
        const float4* wrow = (const float4*)(W2 + h * SD + g * 32);
        float s = 0.f;
        #pragma unroll
        for (int k = 0; k < 8; ++k) {
            const float4 v = wrow[k];
            s += (v.x + v.y) + (v.z + v.w);
        }
        s += __shfl_xor(s, 1);
        s += __shfl_xor(s, 2);
        if (g == 0) sw2[h] = s * (1.0f / SD);
    } else if (tid < 192) {
        // b2bar: one full wave (lanes 0..63), 2 elems/lane
        const int lane = tid & 63;
        float s = b2[lane] + b2[lane + 64];
        s += __shfl_xor(s, 1);
        s += __shfl_xor(s, 2);
        s += __shfl_xor(s, 4);
        s += __shfl_xor(s, 8);
        s += __shfl_xor(s, 16);
        s += __shfl_xor(s, 32);
        if (lane == 0) sb2bar = s * (1.0f / SD);
    } else {
        // seasonal amplitudes: 64 threads x 2 exps
        const int j = tid - 192;
        samp[j]      = expf(log_amp[j * 12 + month]);
        samp[j + 64] = expf(log_amp[(j + 64) * 12 + month]);
    }
    __syncthreads();

    const int l   = tid & (LPR - 1);
    const int r   = tid / LPR;
    const int row = base + r;
    const int h0  = l * 2;

    // ---- z = relu(feat @ W1 + b1), 2 hidden units per lane ----
    float acc0 = b1[h0];
    float acc1 = b1[h0 + 1];
    const float* xr = &sx[r * XS];
    #pragma unroll 8
    for (int n = 0; n < SD; ++n) {
        const float f = xr[n];
        const float2 w = *(const float2*)&sW1[n * HID + h0];
        acc0 = fmaf(f, w.x, acc0);
        acc1 = fmaf(f, w.y, acc1);
    }
    {   // n = 128: the sin-embedding feature
        const float2 w = *(const float2*)&sW1[SD * HID + h0];
        acc0 = fmaf(emb, w.x, acc0);
        acc1 = fmaf(emb, w.y, acc1);
    }

    // ---- m = z . w2bar (+ b2bar), reduced over the 16 lanes of this row ----
    float part = fmaxf(acc0, 0.f) * sw2[h0] + fmaxf(acc1, 0.f) * sw2[h0 + 1];
    part += __shfl_xor(part, 1);
    part += __shfl_xor(part, 2);
    part += __shfl_xor(part, 4);
    part += __shfl_xor(part, 8);
    const float m  = part + sb2bar;
    const float sp = (m > 0.f) ? (m + log1pf(expf(-m))) : log1pf(expf(m));

    // ---- out[row, j] = amp[j] * softplus(m), 8 columns per lane ----
    float* orow = out + (size_t)row * SD + l * 8;
    #pragma unroll
    for (int q = 0; q < 2; ++q) {
        const float* a = &samp[l * 8 + q * 4];
        float4 v;
        v.x = a[0] * sp; v.y = a[1] * sp; v.z = a[2] * sp; v.w = a[3] * sp;
        *(float4*)(orow + q * 4) = v;
    }
}

extern "C" void kernel_launch(void* const* d_in, const int* in_sizes, int n_in,
                              void* d_out, int out_size, void* d_ws, size_t ws_size,
                              hipStream_t stream) {
    const float* x  = (const float*)d_in[0];
    const float* t  = (const float*)d_in[1];
    const float* la = (const float*)d_in[2];
    const float* W1 = (const float*)d_in[3];
    const float* b1 = (const float*)d_in[4];
    const float* W2 = (const float*)d_in[5];
    const float* b2 = (const float*)d_in[6];
    float* out = (float*)d_out;

    gnm_kernel<<<BATCHN / ROWS, 256, 0, stream>>>(x, t, la, W1, b1, W2, b2, out);
}